// Round 9
// baseline (214.180 us; speedup 1.0000x reference)
//
#include <hip/hip_runtime.h>

#define C_     20
#define H_     64
#define W_     2048
#define HW_    (H_*W_)
#define KN     24          // 5x5 taps minus center
#define TH     8
#define TW     64
#define TR     (TH+4)      // 12
#define TC     (TW+4)      // 68
#define PLANE  (TR*TC)     // 816
#define DELEMS (C_*PLANE)  // 16320
#define DPAD   16384       // 16*1024
#define NTHR   1024
#define NPX    512         // pixels per block
#define DSTG   16

#define GLOAD_LDS(SRC, DST)                                                     \
    __builtin_amdgcn_global_load_lds(                                           \
        (const __attribute__((address_space(1))) void*)(SRC),                   \
        (__attribute__((address_space(3))) void*)(DST), 4, 0, 0)

constexpr int KI[KN] = {0,0,0,0,0, 1,1,1,1,1, 2,2,2,2, 3,3,3,3,3, 4,4,4,4,4};
constexpr int KJ[KN] = {0,1,2,3,4, 0,1,2,3,4, 0,1,3,4, 0,1,2,3,4, 0,1,2,3,4};

// Thread (pixel, half HF) computes classes HF*10..HF*10+9 completely
// (a and ba exact), plus partial bi[20]. All indices compile-time.
template<int HF>
__device__ __forceinline__ void compute_half(
    const float* __restrict__ s_data, const float* __restrict__ s_mask,
    int lyy, int lx,
    const float* __restrict__ ang_w, const float* __restrict__ bi_w,
    const float (&bb)[KN],
    float (&bi)[C_], float (&ba_own)[10], float* __restrict__ aout)
{
#pragma unroll
    for (int cl = 0; cl < 10; ++cl) {
        const int cls = HF*10 + cl;
        float a = 0.0f, ba = 0.0f;
        const float* srow = s_data + cls*PLANE + lyy*TC + lx;
        const float* mrow = s_mask + lyy*TC + lx;
#pragma unroll
        for (int k = 0; k < KN; ++k) {
            const int i = KI[k], j = KJ[k];
            const float v = srow[i*TC + j];       // pairs merge -> ds_read2_b32
            const float m = mrow[i*TC + j];       // mask inline from LDS (low reg pressure)
            a  += ang_w[cls*25 + i*5 + j] * v;    // wave-uniform -> s_load
            ba += bi_w [cls*25 + i*5 + j] * v;
            const int flat = k*C_ + cls;          // torch .view remap (k,cls)->(c',k')
            bi[flat/KN] += bb[flat%KN] * (v * m);
        }
        aout[(size_t)cls*HW_] = a;
        ba_own[cl] = ba;
    }
}

__global__ __launch_bounds__(NTHR) void lp_kernel(
    const float* __restrict__ data,
    const float* __restrict__ mask,
    const float* __restrict__ bilat,
    const float* __restrict__ ang_w,
    const float* __restrict__ bi_w,
    const float* __restrict__ zbuf,
    float* __restrict__ out)
{
    __shared__ float s_data[DPAD];   // 64 KB: 20 class planes; reused for bi-reduction
    __shared__ float s_mask[1024];   // 4 KB

    const int tid = threadIdx.x;
    int bid = blockIdx.x;
    bid = (bid & 7)*64 + (bid >> 3);     // XCD swizzle (512 % 8 == 0, bijective)

    const int tx = bid & 31;
    const int ty = (bid >> 5) & 7;
    const int b  = bid >> 8;
    const int y0 = ty*TH, x0 = tx*TW;

    const float* dbase = data + (size_t)b*C_*HW_;
    const float* mbase = mask + (size_t)b*HW_;
    const int wbase = tid & ~63;

    // ---- async DMA: all 20 class planes (registers untouched) ----
#pragma unroll
    for (int s = 0; s < DSTG; ++s) {
        const int idx = tid + s*NTHR;
        const int cls = idx / PLANE;
        const int rem = idx - cls*PLANE;
        const int r   = rem / TC;
        const int col = rem - r*TC;
        const int gy = y0 + r - 2, gx = x0 + col - 2;
        const bool ok = (idx < DELEMS) & (gy >= 0) & (gy < H_) & (gx >= 0) & (gx < W_);
        const float* src = ok ? (dbase + (size_t)cls*HW_ + (gy*W_ + gx)) : zbuf;
        GLOAD_LDS(src, s_data + s*NTHR + wbase);
    }
    // ---- async DMA: mask tile (one instruction, 1024 >= 816 slots) ----
    {
        const int idx = tid;
        const int r   = idx / TC;
        const int col = idx - r*TC;
        const int gy = y0 + r - 2, gx = x0 + col - 2;
        const bool ok = (idx < PLANE) & (gy >= 0) & (gy < H_) & (gx >= 0) & (gx < W_);
        const float* src = ok ? (mbase + (gy*W_ + gx)) : zbuf;
        GLOAD_LDS(src, s_mask + wbase);
    }

    const int p   = tid & (NPX-1);       // pixel within tile
    const int hf  = tid >> 9;            // class half: wave-uniform (waves 0-7 / 8-15)
    const int lx  = p & 63;
    const int lyy = p >> 6;
    const int y = y0 + lyy, x = x0 + lx;

    // bilateral per-pixel (both halves load same values; L1/L2 dedups)
    float bb[KN];
    {
        const float* bibase = bilat + (size_t)b*KN*HW_ + (size_t)y*W_ + x;
#pragma unroll
        for (int kp = 0; kp < KN; ++kp) bb[kp] = bibase[(size_t)kp*HW_];
    }

    __syncthreads();   // drains all DMA

    const float m_c = s_mask[(lyy + 2)*TC + (lx + 2)];

    float bi[C_];
#pragma unroll
    for (int c = 0; c < C_; ++c) bi[c] = 0.0f;
    float ba_own[10];

    float* aout = out + ((size_t)b*C_*H_ + y)*W_ + x;
    float* bout = aout + (size_t)2*C_*HW_;

    if (hf == 0)
        compute_half<0>(s_data, s_mask, lyy, lx, ang_w, bi_w, bb, bi, ba_own, aout);
    else
        compute_half<1>(s_data, s_mask, lyy, lx, ang_w, bi_w, bb, bi, ba_own, aout);

    // ---- bi reduction across the two halves (s_data reused: 2 x 10 x 512 = 40KB) ----
    __syncthreads();   // all reads of s_data done
    if (hf == 1) {
#pragma unroll
        for (int c = 0; c < 10; ++c) s_data[c*NPX + p] = bi[c];          // send bi1[0..9]
    } else {
#pragma unroll
        for (int c = 0; c < 10; ++c) s_data[(10+c)*NPX + p] = bi[10+c];  // send bi0[10..19]
    }
    __syncthreads();
    if (hf == 0) {
#pragma unroll
        for (int cl = 0; cl < 10; ++cl) {
            const float s = bi[cl] + s_data[cl*NPX + p];
            bout[(size_t)cl*HW_] = m_c * ba_own[cl] * s;
        }
    } else {
#pragma unroll
        for (int cl = 0; cl < 10; ++cl) {
            const int c2 = 10 + cl;
            const float s = bi[c2] + s_data[c2*NPX + p];
            bout[(size_t)c2*HW_] = m_c * ba_own[cl] * s;
        }
    }
}

extern "C" void kernel_launch(void* const* d_in, const int* in_sizes, int n_in,
                              void* d_out, int out_size, void* d_ws, size_t ws_size,
                              hipStream_t stream) {
    const float* data  = (const float*)d_in[0];
    const float* mask  = (const float*)d_in[1];
    const float* bilat = (const float*)d_in[2];
    const float* ang_w = (const float*)d_in[3];
    const float* bi_w  = (const float*)d_in[4];
    float* out = (float*)d_out;

    hipMemsetAsync(d_ws, 0, 256, stream);   // zero word for OOB halo lanes

    const int nblocks = 2 * (H_/TH) * (W_/TW);  // 512 blocks x 1024 thr
    lp_kernel<<<nblocks, NTHR, 0, stream>>>(data, mask, bilat, ang_w, bi_w,
                                            (const float*)d_ws, out);
}

// Round 10
// 68.642 us; speedup vs baseline: 3.1203x; 3.1203x over previous
//
#include <hip/hip_runtime.h>

#define C_     20
#define H_     64
#define W_     2048
#define HW_    (H_*W_)
#define KN     24          // 5x5 taps minus center
#define TH     8
#define TW     32
#define TR     (TH+4)      // 12
#define TC     (TW+4)      // 36
#define PLANE  (TR*TC)     // 432
#define NTHR   256
#define NCH    5           // classes per chunk
#define NCHUNK 4
#define CHELE  (NCH*PLANE) // 2160
#define CSTG   9           // ceil(2160/256)
#define CHPAD  (CSTG*NTHR) // 2304 (tail slots dead pad)
#define MSK    512

// async global->LDS: wave-uniform LDS base (+lane*4 in HW); per-lane global src
#define GLOAD_LDS(SRC, DST)                                                     \
    __builtin_amdgcn_global_load_lds(                                           \
        (const __attribute__((address_space(1))) void*)(SRC),                   \
        (__attribute__((address_space(3))) void*)(DST), 4, 0, 0)

constexpr int KI[KN] = {0,0,0,0,0, 1,1,1,1,1, 2,2,2,2, 3,3,3,3,3, 4,4,4,4,4};
constexpr int KJ[KN] = {0,1,2,3,4, 0,1,2,3,4, 0,1,3,4, 0,1,2,3,4, 0,1,2,3,4};

// Round-7-proven compute body: 5 classes of chunk CH, all indices compile-time.
template<int CH>
__device__ __forceinline__ void compute_chunk(
    const float* __restrict__ sbuf, int lyy, int lx,
    const float* __restrict__ ang_w, const float* __restrict__ bi_w,
    const float (&bb)[KN], const float (&mm)[KN],
    float (&bi)[C_], float (&biang)[C_], float* __restrict__ aout)
{
#pragma unroll
    for (int cl = 0; cl < NCH; ++cl) {
        const int cls = CH*NCH + cl;
        float a = 0.0f, ba = 0.0f;
        const float* srow = sbuf + cl*PLANE + lyy*TC + lx;
#pragma unroll
        for (int k = 0; k < KN; ++k) {
            const int i = KI[k], j = KJ[k];
            const float v = srow[i*TC + j];          // pairs merge -> ds_read2_b32
            a  += ang_w[cls*25 + i*5 + j] * v;       // wave-uniform -> s_load
            ba += bi_w [cls*25 + i*5 + j] * v;
            const int flat = k*C_ + cls;             // torch .view remap (k,cls)->(c',k')
            bi[flat/KN] += bb[flat%KN] * (v * mm[k]);
        }
        aout[(size_t)cls*HW_] = a;
        biang[cls] = ba;
    }
}

__global__ __launch_bounds__(NTHR) void lp_kernel(
    const float* __restrict__ data,
    const float* __restrict__ mask,
    const float* __restrict__ bilat,
    const float* __restrict__ ang_w,
    const float* __restrict__ bi_w,
    const float* __restrict__ zbuf,
    float* __restrict__ out)
{
    __shared__ float s_buf[2*CHPAD];   // 18 KB: double-buffered 5-class chunk
    __shared__ float s_mask[MSK];      // 2 KB   -> total exactly 20 KB -> 8 blocks/CU

    const int tid = threadIdx.x;
    int bid = blockIdx.x;
    bid = (bid & 7)*128 + (bid >> 3);    // XCD swizzle (1024 % 8 == 0, bijective)

    const int tx = bid & 63;             // W/TW = 64
    const int ty = (bid >> 6) & 7;       // H/TH = 8
    const int b  = bid >> 9;
    const int y0 = ty*TH, x0 = tx*TW;

    const float* dbase = data + (size_t)b*C_*HW_;
    const float* mbase = mask + (size_t)b*HW_;
    const int wbase = tid & ~63;

    // DMA one 5-class chunk into buffer BUF (no registers held -> no spill risk)
    #define STAGE(CHUNK, BUF) do {                                                   \
        _Pragma("unroll")                                                            \
        for (int s = 0; s < CSTG; ++s) {                                             \
            const int idx = tid + s*NTHR;                                            \
            const int c   = idx / PLANE;                                             \
            const int rem = idx - c*PLANE;                                           \
            const int r   = rem / TC;                                                \
            const int col = rem - r*TC;                                              \
            const int gy = y0 + r - 2, gx = x0 + col - 2;                            \
            const bool ok = (idx < CHELE) & (gy >= 0) & (gy < H_) &                  \
                            (gx >= 0) & (gx < W_);                                   \
            const float* src = ok                                                    \
                ? (dbase + (size_t)((CHUNK)*NCH + c)*HW_ + (gy*W_ + gx)) : zbuf;     \
            GLOAD_LDS(src, s_buf + (BUF)*CHPAD + s*NTHR + wbase);                    \
        }                                                                            \
    } while (0)

    // ---- phase 0: DMA chunk0 + mask; bilateral reg loads overlap ----
    STAGE(0, 0);
#pragma unroll
    for (int s = 0; s < 2; ++s) {
        const int idx = tid + s*NTHR;
        const int r   = idx / TC;
        const int col = idx - r*TC;
        const int gy = y0 + r - 2, gx = x0 + col - 2;
        const bool ok = (idx < PLANE) & (gy >= 0) & (gy < H_) & (gx >= 0) & (gx < W_);
        const float* src = ok ? (mbase + (gy*W_ + gx)) : zbuf;
        GLOAD_LDS(src, s_mask + s*NTHR + wbase);
    }

    const int lx  = tid & 31;
    const int lyy = tid >> 5;            // 8 tile rows, 2 rows per wave
    const int y = y0 + lyy, x = x0 + lx;

    float bb[KN];
    {
        const float* bibase = bilat + (size_t)b*KN*HW_ + (size_t)y*W_ + x;
#pragma unroll
        for (int kp = 0; kp < KN; ++kp) bb[kp] = bibase[(size_t)kp*HW_];
    }

    __syncthreads();   // drains chunk0 + mask DMA

    // ---- issue chunk1 DMA; then mask taps -> regs; then compute chunk0 ----
    STAGE(1, 1);

    float mm[KN];
#pragma unroll
    for (int k = 0; k < KN; ++k) mm[k] = s_mask[(lyy + KI[k])*TC + (lx + KJ[k])];
    const float m_c = s_mask[(lyy + 2)*TC + (lx + 2)];

    float bi[C_], biang[C_];
#pragma unroll
    for (int c = 0; c < C_; ++c) bi[c] = 0.0f;

    float* aout = out + ((size_t)b*C_*H_ + y)*W_ + x;
    float* bout = aout + (size_t)2*C_*HW_;

    compute_chunk<0>(s_buf,         lyy, lx, ang_w, bi_w, bb, mm, bi, biang, aout);
    __syncthreads();                       // chunk1 ready; buf0 reads done

    STAGE(2, 0);
    compute_chunk<1>(s_buf + CHPAD, lyy, lx, ang_w, bi_w, bb, mm, bi, biang, aout);
    __syncthreads();                       // chunk2 ready; buf1 reads done

    STAGE(3, 1);
    compute_chunk<2>(s_buf,         lyy, lx, ang_w, bi_w, bb, mm, bi, biang, aout);
    __syncthreads();                       // chunk3 ready; buf0 reads done

    compute_chunk<3>(s_buf + CHPAD, lyy, lx, ang_w, bi_w, bb, mm, bi, biang, aout);

#pragma unroll
    for (int c = 0; c < C_; ++c)
        bout[(size_t)c*HW_] = m_c * biang[c] * bi[c];

    #undef STAGE
}

extern "C" void kernel_launch(void* const* d_in, const int* in_sizes, int n_in,
                              void* d_out, int out_size, void* d_ws, size_t ws_size,
                              hipStream_t stream) {
    const float* data  = (const float*)d_in[0];
    const float* mask  = (const float*)d_in[1];
    const float* bilat = (const float*)d_in[2];
    const float* ang_w = (const float*)d_in[3];
    const float* bi_w  = (const float*)d_in[4];
    float* out = (float*)d_out;

    hipMemsetAsync(d_ws, 0, 256, stream);   // zero word for OOB halo lanes

    const int nblocks = 2 * (H_/TH) * (W_/TW);  // 1024
    lp_kernel<<<nblocks, NTHR, 0, stream>>>(data, mask, bilat, ang_w, bi_w,
                                            (const float*)d_ws, out);
}